// Round 8
// baseline (289.246 us; speedup 1.0000x reference)
//
#include <hip/hip_runtime.h>
#include <stdint.h>

#define B_ 4
#define C_ 2048
#define L_ 4096
#define M_ 256
#define M3_ 768
#define SLOPE_ 0.2f
#define SPLIT_ 4
#define KVB_ 32

typedef __attribute__((ext_vector_type(8))) short short8;
typedef __attribute__((ext_vector_type(4))) float f32x4;

__device__ __forceinline__ unsigned short f2bf(float f) {
    union { float f; unsigned u; } v; v.f = f;
    unsigned r = v.u + 0x7FFF + ((v.u >> 16) & 1);   // RNE
    return (unsigned short)(r >> 16);
}
__device__ __forceinline__ unsigned short f2bf_rz(float f) {
    union { float f; unsigned u; } v; v.f = f;
    return (unsigned short)(v.u >> 16);              // truncate (for P>0)
}
__device__ __forceinline__ unsigned pack2(float a, float b) {
    return (unsigned)f2bf(a) | ((unsigned)f2bf(b) << 16);
}
__device__ __forceinline__ float lrelu(float v) { return v >= 0.f ? v : SLOPE_ * v; }

__device__ __forceinline__ void gload_lds16(const void* g, void* l) {
    __builtin_amdgcn_global_load_lds(
        (const __attribute__((address_space(1))) void*)g,
        (__attribute__((address_space(3))) void*)l, 16, 0, 0);
}

// ---------------------------------------------------------------------------
// prep_x: x [B][C][L] fp32 -> xT [B][L][C] bf16 (unchanged).
// ---------------------------------------------------------------------------
__global__ __launch_bounds__(256) void prep_x(
    const float* __restrict__ x, unsigned short* __restrict__ xT)
{
    const int l = blockIdx.x * 64 + (threadIdx.x & 63);
    const int c = blockIdx.y * 32 + (threadIdx.x >> 6) * 8;
    const int b = blockIdx.z;
    const float* src = x + ((size_t)b * C_ + c) * L_ + l;
    unsigned v[4];
    #pragma unroll
    for (int j = 0; j < 4; ++j)
        v[j] = pack2(src[(size_t)(2 * j) * L_], src[(size_t)(2 * j + 1) * L_]);
    *reinterpret_cast<uint4*>(&xT[((size_t)b * L_ + l) * C_ + c]) =
        *reinterpret_cast<uint4*>(v);
}

// ---------------------------------------------------------------------------
// prep_w (unchanged).
// ---------------------------------------------------------------------------
__global__ __launch_bounds__(256) void prep_w(
    const float* __restrict__ Wt, const float* __restrict__ Wp,
    const float* __restrict__ Wg, const float* __restrict__ Wo,
    unsigned short* __restrict__ w3, unsigned short* __restrict__ wo)
{
    const size_t NW = (size_t)M_ * C_;
    size_t e = ((size_t)blockIdx.x * 256 + threadIdx.x) * 8;
    const float* src; unsigned short* dst;
    if (e < NW)          { src = Wt + e;          dst = w3 + e; }
    else if (e < 2 * NW) { src = Wp + (e - NW);   dst = w3 + e; }
    else if (e < 3 * NW) { src = Wg + (e - 2*NW); dst = w3 + e; }
    else                 { src = Wo + (e - 3*NW); dst = wo + (e - 3*NW); }
    float4 a = *reinterpret_cast<const float4*>(src);
    float4 b = *reinterpret_cast<const float4*>(src + 4);
    unsigned v[4] = { pack2(a.x, a.y), pack2(a.z, a.w),
                      pack2(b.x, b.y), pack2(b.z, b.w) };
    *reinterpret_cast<uint4*>(dst) = *reinterpret_cast<uint4*>(v);
}

// ---------------------------------------------------------------------------
// proj_kernel v3 (unchanged from round 6).
// ---------------------------------------------------------------------------
__global__ __launch_bounds__(256) void proj_kernel(
    const unsigned short* __restrict__ w3,
    const float* __restrict__ bt, const float* __restrict__ bp,
    const float* __restrict__ bg,
    const unsigned short* __restrict__ xT,
    unsigned short* __restrict__ theta,
    unsigned short* __restrict__ phi,
    unsigned short* __restrict__ gammaT)
{
    __shared__ unsigned short As[2][128 * 64];
    __shared__ unsigned short Bs[2][128 * 64];

    const int l0 = blockIdx.x * 128;
    const int m0 = blockIdx.y * 128;
    const int b  = blockIdx.z;
    const int t  = threadIdx.x;
    const int wave = t >> 6, lane = t & 63;
    const int lr = lane & 15, lg = lane >> 4;
    const int wm = (wave >> 1) * 64, wl = (wave & 1) * 64;

    const int which = m0 >> 8;
    const float* bsrc = (which == 0) ? bt : (which == 1) ? bp : bg;
    const int mw = m0 & 255;

    const unsigned short* abase = w3 + (size_t)m0 * C_;
    const unsigned short* bbase = xT + ((size_t)b * L_ + l0) * C_;

    const int srow = lane >> 3;
    const int scol = ((lane & 7) ^ srow) * 8;

    auto stage = [&](unsigned short* A, unsigned short* Bb, int k0) {
        #pragma unroll
        for (int i = 0; i < 4; ++i) {
            int chunk = wave * 4 + i;
            int row = chunk * 8 + srow;
            gload_lds16(abase + (size_t)row * C_ + k0 + scol, A + chunk * 512);
            gload_lds16(bbase + (size_t)row * C_ + k0 + scol, Bb + chunk * 512);
        }
    };

    f32x4 acc[4][4] = {};

    stage(As[0], Bs[0], 0);
    __syncthreads();

    int cur = 0;
    for (int k0 = 0; k0 < C_; k0 += 64) {
        if (k0 + 64 < C_) stage(As[cur ^ 1], Bs[cur ^ 1], k0 + 64);

        #pragma unroll
        for (int ks = 0; ks < 2; ++ks) {
            short8 af[4], bf[4];
            #pragma unroll
            for (int mi = 0; mi < 4; ++mi)
                af[mi] = *reinterpret_cast<const short8*>(
                    &As[cur][(wm + mi * 16 + lr) * 64 +
                             ((ks * 32 + lg * 8) ^ ((lr & 7) << 3))]);
            #pragma unroll
            for (int ni = 0; ni < 4; ++ni)
                bf[ni] = *reinterpret_cast<const short8*>(
                    &Bs[cur][(wl + ni * 16 + lr) * 64 +
                             ((ks * 32 + lg * 8) ^ ((lr & 7) << 3))]);
            #pragma unroll
            for (int mi = 0; mi < 4; ++mi)
                #pragma unroll
                for (int ni = 0; ni < 4; ++ni)
                    acc[mi][ni] = __builtin_amdgcn_mfma_f32_16x16x32_bf16(
                        af[mi], bf[ni], acc[mi][ni], 0, 0, 0);
        }
        __syncthreads();
        cur ^= 1;
    }

    if (which < 2) {
        unsigned short* dst = (which == 0) ? theta : phi;
        const float scale = (which == 1) ? 0.03125f : 1.0f;
        #pragma unroll
        for (int mi = 0; mi < 4; ++mi) {
            const int mloc = mw + wm + mi * 16 + lg * 4;
            float b0 = bsrc[mloc], b1 = bsrc[mloc + 1];
            float b2 = bsrc[mloc + 2], b3 = bsrc[mloc + 3];
            #pragma unroll
            for (int ni = 0; ni < 4; ++ni) {
                int l = l0 + wl + ni * 16 + lr;
                uint2 pk;
                pk.x = pack2(lrelu(acc[mi][ni][0] + b0) * scale,
                             lrelu(acc[mi][ni][1] + b1) * scale);
                pk.y = pack2(lrelu(acc[mi][ni][2] + b2) * scale,
                             lrelu(acc[mi][ni][3] + b3) * scale);
                *reinterpret_cast<uint2*>(&dst[((size_t)b * L_ + l) * M_ + mloc]) = pk;
            }
        }
    } else {
        #pragma unroll
        for (int mi = 0; mi < 4; ++mi) {
            #pragma unroll
            for (int r = 0; r < 4; ++r) {
                int m = mw + wm + mi * 16 + lg * 4 + r;
                float bias = bsrc[m];
                #pragma unroll
                for (int ni = 0; ni < 4; ++ni) {
                    int l = l0 + wl + ni * 16 + lr;
                    gammaT[((size_t)b * M_ + m) * L_ + l] =
                        f2bf(lrelu(acc[mi][ni][r] + bias));
                }
            }
        }
    }
}

// ---------------------------------------------------------------------------
// attn v6: 8-wave 256-q blocks + TRIPLE-buffered K/V with counted vmcnt
// (T3/T4): prefetch depth 2, per-iter barrier = s_waitcnt vmcnt(4) +
// raw s_barrier (never drain to 0 until the last tile).  LDS 117KB, 1 blk/CU.
// ---------------------------------------------------------------------------
__global__ __launch_bounds__(512, 1) void attn_kernel(
    const unsigned short* __restrict__ phi,     // pre-scaled by 1/32
    const unsigned short* __restrict__ theta,
    const unsigned short* __restrict__ gammaT,
    float* __restrict__ yp,
    float* __restrict__ rsp)
{
    __shared__ unsigned short Ks[3][KVB_ * 256];   // 16KB each, swizzled
    __shared__ unsigned short Vs[3][256 * KVB_];   // 16KB each, swizzled
    __shared__ unsigned short Ps[8][32][42];       // per-wave P

    const int q0 = blockIdx.x * 256;
    const int s  = blockIdx.y;
    const int b  = blockIdx.z;
    const int kvbase = s * (L_ / SPLIT_);
    const int t  = threadIdx.x;
    const int wave = t >> 6, lane = t & 63;
    const int lr = lane & 15, lg = lane >> 4;

    const unsigned short* theta_b = theta  + (size_t)b * L_ * M_;
    const unsigned short* gamma_b = gammaT + (size_t)b * M_ * L_;

    // 512 threads stage 1024 chunks of 16B: 2 per thread.
    auto stage_k = [&](unsigned short* buf, int kv0) {
        #pragma unroll
        for (int q = 0; q < 2; ++q) {
            int c   = q * 512 + t;
            int row = c >> 5;
            int cb  = (c & 31) << 4;
            int cbs = cb ^ ((row & 7) << 4);
            const unsigned short* src = theta_b + (size_t)(kv0 + row) * M_ + (cbs >> 1);
            unsigned short* ldst = buf + ((size_t)(q * 512 + wave * 64) << 3);
            gload_lds16(src, ldst);
        }
    };
    auto stage_v = [&](unsigned short* buf, int kv0) {
        #pragma unroll
        for (int q = 0; q < 2; ++q) {
            int c  = q * 512 + t;
            int mh = c >> 3;
            int tb = ((c & 7) << 4) ^ ((mh & 7) << 4);
            int m  = mh * 2 + (tb >> 6);
            int j  = (tb & 63) >> 1;
            const unsigned short* src = gamma_b + (size_t)m * L_ + kv0 + j;
            unsigned short* ldst = buf + ((size_t)(q * 512 + wave * 64) << 3);
            gload_lds16(src, ldst);
        }
    };

    // prologue: 2 tiles in flight BEFORE the Q loads (issue order pinned)
    stage_k(&Ks[0][0], kvbase);
    stage_v(&Vs[0][0], kvbase);
    stage_k(&Ks[1][0], kvbase + KVB_);
    stage_v(&Vs[1][0], kvbase + KVB_);
    __builtin_amdgcn_sched_barrier(0);

    // Q in registers: subtile u -> rows q0 + wave*32 + u*16
    short8 qf[2][8];
    #pragma unroll
    for (int u = 0; u < 2; ++u) {
        const unsigned short* qrow =
            phi + ((size_t)b * L_ + q0 + wave * 32 + u * 16 + lr) * M_ + lg * 8;
        #pragma unroll
        for (int ks = 0; ks < 8; ++ks)
            qf[u][ks] = *reinterpret_cast<const short8*>(qrow + ks * 32);
    }

    f32x4 accy[2][16] = {};
    float rsum[2][4] = {};

    const int NT = L_ / SPLIT_ / KVB_;   // 32
    for (int it = 0; it < NT; ++it) {
        const int cur = it % 3;
        // wait for buf[cur]'s 4 loads (leave the newer prefetch in flight)
        if (it < NT - 1) asm volatile("s_waitcnt vmcnt(4)" ::: "memory");
        else             asm volatile("s_waitcnt vmcnt(0)" ::: "memory");
        __builtin_amdgcn_sched_barrier(0);
        __builtin_amdgcn_s_barrier();
        __builtin_amdgcn_sched_barrier(0);

        // issue prefetch for it+2 (buffer (it+2)%3 was last read at it-1,
        // and every wave passed the barrier above after finishing it-1)
        if (it + 2 < NT) {
            stage_k(&Ks[(it + 2) % 3][0], kvbase + (it + 2) * KVB_);
            stage_v(&Vs[(it + 2) % 3][0], kvbase + (it + 2) * KVB_);
            __builtin_amdgcn_sched_barrier(0);
        }

        const unsigned short* kb = &Ks[cur][0];
        const unsigned short* vb = &Vs[cur][0];

        // S = Q K^T : 32 MFMA, K fragments shared across the 2 q-subtiles
        f32x4 sacc[2][2] = {};
        __builtin_amdgcn_s_setprio(1);
        #pragma unroll
        for (int ks = 0; ks < 8; ++ks) {
            #pragma unroll
            for (int jt = 0; jt < 2; ++jt) {
                int jr = jt * 16 + lr;
                int cbl = ks * 64 + lg * 16;
                short8 bf = *reinterpret_cast<const short8*>(
                    &kb[jr * 256 + (((cbl ^ ((jr & 7) << 4)) >> 1))]);
                sacc[0][jt] = __builtin_amdgcn_mfma_f32_16x16x32_bf16(qf[0][ks], bf, sacc[0][jt], 0, 0, 0);
                sacc[1][jt] = __builtin_amdgcn_mfma_f32_16x16x32_bf16(qf[1][ks], bf, sacc[1][jt], 0, 0, 0);
            }
        }
        __builtin_amdgcn_s_setprio(0);

        // P = exp(s) (phi pre-scaled); truncating bf16; per-lane row sums
        #pragma unroll
        for (int u = 0; u < 2; ++u)
            #pragma unroll
            for (int jt = 0; jt < 2; ++jt)
                #pragma unroll
                for (int r = 0; r < 4; ++r) {
                    float p = __expf(sacc[u][jt][r]);
                    rsum[u][r] += p;
                    Ps[wave][u * 16 + lg * 4 + r][lr + 16 * jt] = f2bf_rz(p);
                }

        // y += P V^T : 32 MFMA, V fragments shared across subtiles
        short8 paf[2];
        paf[0] = *reinterpret_cast<const short8*>(&Ps[wave][lr][lg * 8]);
        paf[1] = *reinterpret_cast<const short8*>(&Ps[wave][16 + lr][lg * 8]);
        __builtin_amdgcn_s_setprio(1);
        #pragma unroll
        for (int mt = 0; mt < 16; ++mt) {
            int m = mt * 16 + lr;
            int byte = (m >> 1) * 128 +
                       ((((m & 1) * 64 + lg * 16)) ^ (((m >> 1) & 7) << 4));
            short8 bf = *reinterpret_cast<const short8*>(&vb[byte >> 1]);
            accy[0][mt] = __builtin_amdgcn_mfma_f32_16x16x32_bf16(paf[0], bf, accy[0][mt], 0, 0, 0);
            accy[1][mt] = __builtin_amdgcn_mfma_f32_16x16x32_bf16(paf[1], bf, accy[1][mt], 0, 0, 0);
        }
        __builtin_amdgcn_s_setprio(0);
        // no trailing barrier: next iteration's [vmcnt + s_barrier] covers it
    }

    // epilogue: unnormalized fp32 partials + row-sum partials
    float* ypb = yp + (((size_t)(s * B_ + b) * L_) + q0) * M_;
    #pragma unroll
    for (int u = 0; u < 2; ++u)
        #pragma unroll
        for (int r = 0; r < 4; ++r) {
            int row = wave * 32 + u * 16 + lg * 4 + r;
            #pragma unroll
            for (int mt = 0; mt < 16; ++mt)
                ypb[(size_t)row * M_ + lr + 16 * mt] = accy[u][mt][r];
            float ssum = rsum[u][r];
            #pragma unroll
            for (int off = 1; off < 16; off <<= 1)
                ssum += __shfl_xor(ssum, off, 64);
            if (lr == 0)
                rsp[((size_t)(s * B_ + b) * L_) + q0 + row] = ssum;
        }
}

// ---------------------------------------------------------------------------
// reduce_kernel (unchanged).
// ---------------------------------------------------------------------------
__global__ __launch_bounds__(256) void reduce_kernel(
    const float* __restrict__ yp,
    const float* __restrict__ rsp,
    unsigned short* __restrict__ y)
{
    const int idx = blockIdx.x * 256 + threadIdx.x;
    const int ml  = (idx * 8) & (M_ - 1);
    const int row = (idx * 8) >> 8;
    const int b   = row >> 12;
    const int l   = row & (L_ - 1);

    float acc[8] = {};
    float rs = 0.f;
    #pragma unroll
    for (int s = 0; s < SPLIT_; ++s) {
        const float* p = yp + (((size_t)(s * B_ + b) * L_) + l) * M_ + ml;
        float4 a = *reinterpret_cast<const float4*>(p);
        float4 c = *reinterpret_cast<const float4*>(p + 4);
        acc[0] += a.x; acc[1] += a.y; acc[2] += a.z; acc[3] += a.w;
        acc[4] += c.x; acc[5] += c.y; acc[6] += c.z; acc[7] += c.w;
        rs += rsp[((size_t)(s * B_ + b) * L_) + l];
    }
    float inv = 1.f / rs;
    unsigned v[4] = { pack2(acc[0] * inv, acc[1] * inv),
                      pack2(acc[2] * inv, acc[3] * inv),
                      pack2(acc[4] * inv, acc[5] * inv),
                      pack2(acc[6] * inv, acc[7] * inv) };
    *reinterpret_cast<uint4*>(&y[((size_t)b * L_ + l) * M_ + ml]) =
        *reinterpret_cast<uint4*>(v);
}

// ---------------------------------------------------------------------------
// out_kernel v3 (unchanged from round 6).
// ---------------------------------------------------------------------------
__global__ __launch_bounds__(256) void out_kernel(
    const float* __restrict__ x,
    const unsigned short* __restrict__ wo,
    const float* __restrict__ bo,
    const unsigned short* __restrict__ y,
    float* __restrict__ out)
{
    __shared__ unsigned short As[2][128 * 64];
    __shared__ unsigned short Bs[2][128 * 64];

    const int l0 = blockIdx.x * 128;
    const int c0 = blockIdx.y * 128;
    const int b  = blockIdx.z;
    const int t  = threadIdx.x;
    const int wave = t >> 6, lane = t & 63;
    const int lr = lane & 15, lg = lane >> 4;
    const int wm = (wave >> 1) * 64, wl = (wave & 1) * 64;

    const unsigned short* abase = wo + (size_t)c0 * M_;
    const unsigned short* bbase = y + ((size_t)b * L_ + l0) * M_;

    const int srow = lane >> 3;
    const int scol = ((lane & 7) ^ srow) * 8;

    auto stage = [&](unsigned short* A, unsigned short* Bb, int k0) {
        #pragma unroll
        for (int i = 0; i < 4; ++i) {
            int chunk = wave * 4 + i;
            int row = chunk * 8 + srow;
            gload_lds16(abase + (size_t)row * M_ + k0 + scol, A + chunk * 512);
            gload_lds16(bbase + (size_t)row * M_ + k0 + scol, Bb + chunk * 512);
        }
    };

    f32x4 acc[4][4] = {};

    stage(As[0], Bs[0], 0);
    __syncthreads();

    int cur = 0;
    for (int k0 = 0; k0 < M_; k0 += 64) {
        if (k0 + 64 < M_) stage(As[cur ^ 1], Bs[cur ^ 1], k0 + 64);

        #pragma unroll
        for (int ks = 0; ks < 2; ++ks) {
            short8 af[4], bf[4];
            #pragma unroll
            for (int mi = 0; mi < 4; ++mi)
                af[mi] = *reinterpret_cast<const short8*>(
                    &As[cur][(wm + mi * 16 + lr) * 64 +
                             ((ks * 32 + lg * 8) ^ ((lr & 7) << 3))]);
            #pragma unroll
            for (int ni = 0; ni < 4; ++ni)
                bf[ni] = *reinterpret_cast<const short8*>(
                    &Bs[cur][(wl + ni * 16 + lr) * 64 +
                             ((ks * 32 + lg * 8) ^ ((lr & 7) << 3))]);
            #pragma unroll
            for (int mi = 0; mi < 4; ++mi)
                #pragma unroll
                for (int ni = 0; ni < 4; ++ni)
                    acc[mi][ni] = __builtin_amdgcn_mfma_f32_16x16x32_bf16(
                        af[mi], bf[ni], acc[mi][ni], 0, 0, 0);
        }
        __syncthreads();
        cur ^= 1;
    }

    #pragma unroll
    for (int mi = 0; mi < 4; ++mi) {
        #pragma unroll
        for (int r = 0; r < 4; ++r) {
            int c = c0 + wm + mi * 16 + lg * 4 + r;
            float bias = bo[c];
            #pragma unroll
            for (int ni = 0; ni < 4; ++ni) {
                int l = l0 + wl + ni * 16 + lr;
                size_t idx = ((size_t)b * C_ + c) * L_ + l;
                out[idx] = x[idx] + lrelu(acc[mi][ni][r] + bias);
            }
        }
    }
}

// ---------------------------------------------------------------------------
extern "C" void kernel_launch(void* const* d_in, const int* in_sizes, int n_in,
                              void* d_out, int out_size, void* d_ws, size_t ws_size,
                              hipStream_t stream) {
    const float* x  = (const float*)d_in[0];
    const float* Wt = (const float*)d_in[1];
    const float* bt = (const float*)d_in[2];
    const float* Wp = (const float*)d_in[3];
    const float* bp = (const float*)d_in[4];
    const float* Wg = (const float*)d_in[5];
    const float* bg = (const float*)d_in[6];
    const float* Wo = (const float*)d_in[7];
    const float* bo = (const float*)d_in[8];
    float* out = (float*)d_out;

    unsigned short* xT    = (unsigned short*)d_ws;                  // [B][L][C]  64MB
    unsigned short* w3    = xT + (size_t)B_ * L_ * C_;              // [768][C]   3MB
    unsigned short* wob   = w3 + (size_t)M3_ * C_;                  // [C][M]     1MB
    unsigned short* theta = wob + (size_t)C_ * M_;                  // [B][L][M]  8MB
    unsigned short* phi   = theta + (size_t)B_ * L_ * M_;
    unsigned short* gammaT= phi   + (size_t)B_ * L_ * M_;           // [B][M][L]

    float* yp  = (float*)xT;     // [SPLIT][B][L][M] fp32, 64MB (xT dead after proj)
    float* rsp = (float*)w3;     // [SPLIT][B][L]    fp32 (w3 dead after proj)
    unsigned short* yb = theta;  // [B][L][M] bf16 (theta dead after attn)

    prep_x<<<dim3(L_ / 64, C_ / 32, B_), 256, 0, stream>>>(x, xT);
    prep_w<<<dim3(2097152 / 8 / 256), 256, 0, stream>>>(Wt, Wp, Wg, Wo, w3, wob);
    proj_kernel<<<dim3(L_ / 128, M3_ / 128, B_), 256, 0, stream>>>(
        w3, bt, bp, bg, xT, theta, phi, gammaT);
    attn_kernel<<<dim3(L_ / 256, SPLIT_, B_), 512, 0, stream>>>(
        phi, theta, gammaT, yp, rsp);
    reduce_kernel<<<dim3((B_ * L_ * M_ / 8) / 256), 256, 0, stream>>>(yp, rsp, yb);
    out_kernel<<<dim3(L_ / 128, C_ / 128, B_), 256, 0, stream>>>(x, wob, bo, yb, out);
}

// Round 9
// 269.530 us; speedup vs baseline: 1.0732x; 1.0732x over previous
//
#include <hip/hip_runtime.h>
#include <stdint.h>

#define B_ 4
#define C_ 2048
#define L_ 4096
#define M_ 256
#define M3_ 768
#define SLOPE_ 0.2f
#define SPLIT_ 4
#define KVB_ 32

typedef __attribute__((ext_vector_type(8))) short short8;
typedef __attribute__((ext_vector_type(4))) float f32x4;

__device__ __forceinline__ unsigned short f2bf(float f) {
    union { float f; unsigned u; } v; v.f = f;
    unsigned r = v.u + 0x7FFF + ((v.u >> 16) & 1);   // RNE
    return (unsigned short)(r >> 16);
}
__device__ __forceinline__ unsigned short f2bf_rz(float f) {
    union { float f; unsigned u; } v; v.f = f;
    return (unsigned short)(v.u >> 16);              // truncate (for P>0)
}
__device__ __forceinline__ unsigned pack2(float a, float b) {
    return (unsigned)f2bf(a) | ((unsigned)f2bf(b) << 16);
}
__device__ __forceinline__ float lrelu(float v) { return v >= 0.f ? v : SLOPE_ * v; }

__device__ __forceinline__ void gload_lds16(const void* g, void* l) {
    __builtin_amdgcn_global_load_lds(
        (const __attribute__((address_space(1))) void*)g,
        (__attribute__((address_space(3))) void*)l, 16, 0, 0);
}

// ---------------------------------------------------------------------------
// prep_x: x [B][C][L] fp32 -> xT [B][L][C] bf16 (unchanged).
// ---------------------------------------------------------------------------
__global__ __launch_bounds__(256) void prep_x(
    const float* __restrict__ x, unsigned short* __restrict__ xT)
{
    const int l = blockIdx.x * 64 + (threadIdx.x & 63);
    const int c = blockIdx.y * 32 + (threadIdx.x >> 6) * 8;
    const int b = blockIdx.z;
    const float* src = x + ((size_t)b * C_ + c) * L_ + l;
    unsigned v[4];
    #pragma unroll
    for (int j = 0; j < 4; ++j)
        v[j] = pack2(src[(size_t)(2 * j) * L_], src[(size_t)(2 * j + 1) * L_]);
    *reinterpret_cast<uint4*>(&xT[((size_t)b * L_ + l) * C_ + c]) =
        *reinterpret_cast<uint4*>(v);
}

// ---------------------------------------------------------------------------
// prep_w (unchanged).
// ---------------------------------------------------------------------------
__global__ __launch_bounds__(256) void prep_w(
    const float* __restrict__ Wt, const float* __restrict__ Wp,
    const float* __restrict__ Wg, const float* __restrict__ Wo,
    unsigned short* __restrict__ w3, unsigned short* __restrict__ wo)
{
    const size_t NW = (size_t)M_ * C_;
    size_t e = ((size_t)blockIdx.x * 256 + threadIdx.x) * 8;
    const float* src; unsigned short* dst;
    if (e < NW)          { src = Wt + e;          dst = w3 + e; }
    else if (e < 2 * NW) { src = Wp + (e - NW);   dst = w3 + e; }
    else if (e < 3 * NW) { src = Wg + (e - 2*NW); dst = w3 + e; }
    else                 { src = Wo + (e - 3*NW); dst = wo + (e - 3*NW); }
    float4 a = *reinterpret_cast<const float4*>(src);
    float4 b = *reinterpret_cast<const float4*>(src + 4);
    unsigned v[4] = { pack2(a.x, a.y), pack2(a.z, a.w),
                      pack2(b.x, b.y), pack2(b.z, b.w) };
    *reinterpret_cast<uint4*>(dst) = *reinterpret_cast<uint4*>(v);
}

// ---------------------------------------------------------------------------
// proj_kernel v4: exact m97 single-buffer 2-barrier loop (32KB LDS ->
// 3 blocks/CU with __launch_bounds__(256,3)) + both-sides XOR swizzle.
// grid (32, 6, 4), block 256 (4 waves, 64x64 out each).
// ---------------------------------------------------------------------------
__global__ __launch_bounds__(256, 3) void proj_kernel(
    const unsigned short* __restrict__ w3,
    const float* __restrict__ bt, const float* __restrict__ bp,
    const float* __restrict__ bg,
    const unsigned short* __restrict__ xT,
    unsigned short* __restrict__ theta,
    unsigned short* __restrict__ phi,
    unsigned short* __restrict__ gammaT)
{
    __shared__ unsigned short As[128 * 64];
    __shared__ unsigned short Bs[128 * 64];

    const int l0 = blockIdx.x * 128;
    const int m0 = blockIdx.y * 128;
    const int b  = blockIdx.z;
    const int t  = threadIdx.x;
    const int wave = t >> 6, lane = t & 63;
    const int lr = lane & 15, lg = lane >> 4;
    const int wm = (wave >> 1) * 64, wl = (wave & 1) * 64;

    const int which = m0 >> 8;
    const float* bsrc = (which == 0) ? bt : (which == 1) ? bp : bg;
    const int mw = m0 & 255;

    const unsigned short* abase = w3 + (size_t)m0 * C_;
    const unsigned short* bbase = xT + ((size_t)b * L_ + l0) * C_;

    const int srow = lane >> 3;                     // row within 8-row chunk
    const int scol = ((lane & 7) ^ srow) * 8;       // swizzled source col (elems)

    f32x4 acc[4][4] = {};

    for (int k0 = 0; k0 < C_; k0 += 64) {
        __syncthreads();
        #pragma unroll
        for (int i = 0; i < 4; ++i) {
            int chunk = wave * 4 + i;               // 0..15, 8 rows each
            int row = chunk * 8 + srow;
            gload_lds16(abase + (size_t)row * C_ + k0 + scol, As + chunk * 512);
            gload_lds16(bbase + (size_t)row * C_ + k0 + scol, Bs + chunk * 512);
        }
        __syncthreads();

        #pragma unroll
        for (int ks = 0; ks < 2; ++ks) {
            short8 af[4], bf[4];
            #pragma unroll
            for (int mi = 0; mi < 4; ++mi)
                af[mi] = *reinterpret_cast<const short8*>(
                    &As[(wm + mi * 16 + lr) * 64 +
                        ((ks * 32 + lg * 8) ^ ((lr & 7) << 3))]);
            #pragma unroll
            for (int ni = 0; ni < 4; ++ni)
                bf[ni] = *reinterpret_cast<const short8*>(
                    &Bs[(wl + ni * 16 + lr) * 64 +
                        ((ks * 32 + lg * 8) ^ ((lr & 7) << 3))]);
            #pragma unroll
            for (int mi = 0; mi < 4; ++mi)
                #pragma unroll
                for (int ni = 0; ni < 4; ++ni)
                    acc[mi][ni] = __builtin_amdgcn_mfma_f32_16x16x32_bf16(
                        af[mi], bf[ni], acc[mi][ni], 0, 0, 0);
        }
    }

    if (which < 2) {
        unsigned short* dst = (which == 0) ? theta : phi;
        const float scale = (which == 1) ? 0.03125f : 1.0f;   // fold 1/32 into phi
        #pragma unroll
        for (int mi = 0; mi < 4; ++mi) {
            const int mloc = mw + wm + mi * 16 + lg * 4;
            float b0 = bsrc[mloc], b1 = bsrc[mloc + 1];
            float b2 = bsrc[mloc + 2], b3 = bsrc[mloc + 3];
            #pragma unroll
            for (int ni = 0; ni < 4; ++ni) {
                int l = l0 + wl + ni * 16 + lr;
                uint2 pk;
                pk.x = pack2(lrelu(acc[mi][ni][0] + b0) * scale,
                             lrelu(acc[mi][ni][1] + b1) * scale);
                pk.y = pack2(lrelu(acc[mi][ni][2] + b2) * scale,
                             lrelu(acc[mi][ni][3] + b3) * scale);
                *reinterpret_cast<uint2*>(&dst[((size_t)b * L_ + l) * M_ + mloc]) = pk;
            }
        }
    } else {
        #pragma unroll
        for (int mi = 0; mi < 4; ++mi) {
            #pragma unroll
            for (int r = 0; r < 4; ++r) {
                int m = mw + wm + mi * 16 + lg * 4 + r;
                float bias = bsrc[m];
                #pragma unroll
                for (int ni = 0; ni < 4; ++ni) {
                    int l = l0 + wl + ni * 16 + lr;
                    gammaT[((size_t)b * M_ + m) * L_ + l] =
                        f2bf(lrelu(acc[mi][ni][r] + bias));
                }
            }
        }
    }
}

// ---------------------------------------------------------------------------
// attn v5 (round-7 version, reverted): 8-wave 256-q blocks, double-buffered
// gload_lds staging, both-sides swizzle, __syncthreads per tile.
// ---------------------------------------------------------------------------
__global__ __launch_bounds__(512, 1) void attn_kernel(
    const unsigned short* __restrict__ phi,     // pre-scaled by 1/32
    const unsigned short* __restrict__ theta,
    const unsigned short* __restrict__ gammaT,
    float* __restrict__ yp,
    float* __restrict__ rsp)
{
    __shared__ unsigned short Ks[2][KVB_ * 256];   // 16KB each, swizzled
    __shared__ unsigned short Vs[2][256 * KVB_];   // 16KB each, swizzled
    __shared__ unsigned short Ps[8][32][42];       // per-wave P

    const int q0 = blockIdx.x * 256;
    const int s  = blockIdx.y;
    const int b  = blockIdx.z;
    const int kvbase = s * (L_ / SPLIT_);
    const int t  = threadIdx.x;
    const int wave = t >> 6, lane = t & 63;
    const int lr = lane & 15, lg = lane >> 4;

    const unsigned short* theta_b = theta  + (size_t)b * L_ * M_;
    const unsigned short* gamma_b = gammaT + (size_t)b * M_ * L_;

    // Q in registers: subtile u -> rows q0 + wave*32 + u*16
    short8 qf[2][8];
    #pragma unroll
    for (int u = 0; u < 2; ++u) {
        const unsigned short* qrow =
            phi + ((size_t)b * L_ + q0 + wave * 32 + u * 16 + lr) * M_ + lg * 8;
        #pragma unroll
        for (int ks = 0; ks < 8; ++ks)
            qf[u][ks] = *reinterpret_cast<const short8*>(qrow + ks * 32);
    }

    f32x4 accy[2][16] = {};
    float rsum[2][4] = {};

    // 512 threads stage 1024 chunks of 16B: 2 per thread.
    auto stage_k = [&](unsigned short* buf, int kv0) {
        #pragma unroll
        for (int q = 0; q < 2; ++q) {
            int c   = q * 512 + t;
            int row = c >> 5;
            int cb  = (c & 31) << 4;
            int cbs = cb ^ ((row & 7) << 4);
            const unsigned short* src = theta_b + (size_t)(kv0 + row) * M_ + (cbs >> 1);
            unsigned short* ldst = buf + ((size_t)(q * 512 + wave * 64) << 3);
            gload_lds16(src, ldst);
        }
    };
    auto stage_v = [&](unsigned short* buf, int kv0) {
        #pragma unroll
        for (int q = 0; q < 2; ++q) {
            int c  = q * 512 + t;
            int mh = c >> 3;
            int tb = ((c & 7) << 4) ^ ((mh & 7) << 4);
            int m  = mh * 2 + (tb >> 6);
            int j  = (tb & 63) >> 1;
            const unsigned short* src = gamma_b + (size_t)m * L_ + kv0 + j;
            unsigned short* ldst = buf + ((size_t)(q * 512 + wave * 64) << 3);
            gload_lds16(src, ldst);
        }
    };

    stage_k(&Ks[0][0], kvbase);
    stage_v(&Vs[0][0], kvbase);
    __syncthreads();

    int cur = 0;
    for (int it = 0; it < L_ / SPLIT_ / KVB_; ++it) {
        if (it + 1 < L_ / SPLIT_ / KVB_) {
            stage_k(&Ks[cur ^ 1][0], kvbase + (it + 1) * KVB_);
            stage_v(&Vs[cur ^ 1][0], kvbase + (it + 1) * KVB_);
        }

        // S = Q K^T : 32 MFMA, K fragments shared across the 2 q-subtiles
        f32x4 sacc[2][2] = {};
        __builtin_amdgcn_s_setprio(1);
        #pragma unroll
        for (int ks = 0; ks < 8; ++ks) {
            #pragma unroll
            for (int jt = 0; jt < 2; ++jt) {
                int jr = jt * 16 + lr;
                int cbl = ks * 64 + lg * 16;
                short8 bf = *reinterpret_cast<const short8*>(
                    &Ks[cur][jr * 256 + (((cbl ^ ((jr & 7) << 4)) >> 1))]);
                sacc[0][jt] = __builtin_amdgcn_mfma_f32_16x16x32_bf16(qf[0][ks], bf, sacc[0][jt], 0, 0, 0);
                sacc[1][jt] = __builtin_amdgcn_mfma_f32_16x16x32_bf16(qf[1][ks], bf, sacc[1][jt], 0, 0, 0);
            }
        }
        __builtin_amdgcn_s_setprio(0);

        // P = exp(s) (phi pre-scaled); truncating bf16; per-lane row sums
        #pragma unroll
        for (int u = 0; u < 2; ++u)
            #pragma unroll
            for (int jt = 0; jt < 2; ++jt)
                #pragma unroll
                for (int r = 0; r < 4; ++r) {
                    float p = __expf(sacc[u][jt][r]);
                    rsum[u][r] += p;
                    Ps[wave][u * 16 + lg * 4 + r][lr + 16 * jt] = f2bf_rz(p);
                }

        // y += P V^T : 32 MFMA, V fragments shared across subtiles
        short8 paf[2];
        paf[0] = *reinterpret_cast<const short8*>(&Ps[wave][lr][lg * 8]);
        paf[1] = *reinterpret_cast<const short8*>(&Ps[wave][16 + lr][lg * 8]);
        __builtin_amdgcn_s_setprio(1);
        #pragma unroll
        for (int mt = 0; mt < 16; ++mt) {
            int m = mt * 16 + lr;
            int byte = (m >> 1) * 128 +
                       ((((m & 1) * 64 + lg * 16)) ^ (((m >> 1) & 7) << 4));
            short8 bf = *reinterpret_cast<const short8*>(&Vs[cur][byte >> 1]);
            accy[0][mt] = __builtin_amdgcn_mfma_f32_16x16x32_bf16(paf[0], bf, accy[0][mt], 0, 0, 0);
            accy[1][mt] = __builtin_amdgcn_mfma_f32_16x16x32_bf16(paf[1], bf, accy[1][mt], 0, 0, 0);
        }
        __builtin_amdgcn_s_setprio(0);

        __syncthreads();
        cur ^= 1;
    }

    // epilogue: unnormalized fp32 partials + row-sum partials
    float* ypb = yp + (((size_t)(s * B_ + b) * L_) + q0) * M_;
    #pragma unroll
    for (int u = 0; u < 2; ++u)
        #pragma unroll
        for (int r = 0; r < 4; ++r) {
            int row = wave * 32 + u * 16 + lg * 4 + r;
            #pragma unroll
            for (int mt = 0; mt < 16; ++mt)
                ypb[(size_t)row * M_ + lr + 16 * mt] = accy[u][mt][r];
            float ssum = rsum[u][r];
            #pragma unroll
            for (int off = 1; off < 16; off <<= 1)
                ssum += __shfl_xor(ssum, off, 64);
            if (lr == 0)
                rsp[((size_t)(s * B_ + b) * L_) + q0 + row] = ssum;
        }
}

// ---------------------------------------------------------------------------
// reduce_kernel (unchanged).
// ---------------------------------------------------------------------------
__global__ __launch_bounds__(256) void reduce_kernel(
    const float* __restrict__ yp,
    const float* __restrict__ rsp,
    unsigned short* __restrict__ y)
{
    const int idx = blockIdx.x * 256 + threadIdx.x;
    const int ml  = (idx * 8) & (M_ - 1);
    const int row = (idx * 8) >> 8;
    const int b   = row >> 12;
    const int l   = row & (L_ - 1);

    float acc[8] = {};
    float rs = 0.f;
    #pragma unroll
    for (int s = 0; s < SPLIT_; ++s) {
        const float* p = yp + (((size_t)(s * B_ + b) * L_) + l) * M_ + ml;
        float4 a = *reinterpret_cast<const float4*>(p);
        float4 c = *reinterpret_cast<const float4*>(p + 4);
        acc[0] += a.x; acc[1] += a.y; acc[2] += a.z; acc[3] += a.w;
        acc[4] += c.x; acc[5] += c.y; acc[6] += c.z; acc[7] += c.w;
        rs += rsp[((size_t)(s * B_ + b) * L_) + l];
    }
    float inv = 1.f / rs;
    unsigned v[4] = { pack2(acc[0] * inv, acc[1] * inv),
                      pack2(acc[2] * inv, acc[3] * inv),
                      pack2(acc[4] * inv, acc[5] * inv),
                      pack2(acc[6] * inv, acc[7] * inv) };
    *reinterpret_cast<uint4*>(&y[((size_t)b * L_ + l) * M_ + ml]) =
        *reinterpret_cast<uint4*>(v);
}

// ---------------------------------------------------------------------------
// out_kernel v4: single-buffer m97 2-barrier + swizzle, LB(256,3).
// K=256 (4 iters).  grid (32, 16, 4), block 256.
// ---------------------------------------------------------------------------
__global__ __launch_bounds__(256, 3) void out_kernel(
    const float* __restrict__ x,
    const unsigned short* __restrict__ wo,
    const float* __restrict__ bo,
    const unsigned short* __restrict__ y,
    float* __restrict__ out)
{
    __shared__ unsigned short As[128 * 64];
    __shared__ unsigned short Bs[128 * 64];

    const int l0 = blockIdx.x * 128;
    const int c0 = blockIdx.y * 128;
    const int b  = blockIdx.z;
    const int t  = threadIdx.x;
    const int wave = t >> 6, lane = t & 63;
    const int lr = lane & 15, lg = lane >> 4;
    const int wm = (wave >> 1) * 64, wl = (wave & 1) * 64;

    const unsigned short* abase = wo + (size_t)c0 * M_;
    const unsigned short* bbase = y + ((size_t)b * L_ + l0) * M_;

    const int srow = lane >> 3;
    const int scol = ((lane & 7) ^ srow) * 8;

    f32x4 acc[4][4] = {};

    for (int k0 = 0; k0 < M_; k0 += 64) {
        __syncthreads();
        #pragma unroll
        for (int i = 0; i < 4; ++i) {
            int chunk = wave * 4 + i;
            int row = chunk * 8 + srow;
            gload_lds16(abase + (size_t)row * M_ + k0 + scol, As + chunk * 512);
            gload_lds16(bbase + (size_t)row * M_ + k0 + scol, Bs + chunk * 512);
        }
        __syncthreads();

        #pragma unroll
        for (int ks = 0; ks < 2; ++ks) {
            short8 af[4], bf[4];
            #pragma unroll
            for (int mi = 0; mi < 4; ++mi)
                af[mi] = *reinterpret_cast<const short8*>(
                    &As[(wm + mi * 16 + lr) * 64 +
                        ((ks * 32 + lg * 8) ^ ((lr & 7) << 3))]);
            #pragma unroll
            for (int ni = 0; ni < 4; ++ni)
                bf[ni] = *reinterpret_cast<const short8*>(
                    &Bs[(wl + ni * 16 + lr) * 64 +
                        ((ks * 32 + lg * 8) ^ ((lr & 7) << 3))]);
            #pragma unroll
            for (int mi = 0; mi < 4; ++mi)
                #pragma unroll
                for (int ni = 0; ni < 4; ++ni)
                    acc[mi][ni] = __builtin_amdgcn_mfma_f32_16x16x32_bf16(
                        af[mi], bf[ni], acc[mi][ni], 0, 0, 0);
        }
    }

    #pragma unroll
    for (int mi = 0; mi < 4; ++mi) {
        #pragma unroll
        for (int r = 0; r < 4; ++r) {
            int c = c0 + wm + mi * 16 + lg * 4 + r;
            float bias = bo[c];
            #pragma unroll
            for (int ni = 0; ni < 4; ++ni) {
                int l = l0 + wl + ni * 16 + lr;
                size_t idx = ((size_t)b * C_ + c) * L_ + l;
                out[idx] = x[idx] + lrelu(acc[mi][ni][r] + bias);
            }
        }
    }
}

// ---------------------------------------------------------------------------
extern "C" void kernel_launch(void* const* d_in, const int* in_sizes, int n_in,
                              void* d_out, int out_size, void* d_ws, size_t ws_size,
                              hipStream_t stream) {
    const float* x  = (const float*)d_in[0];
    const float* Wt = (const float*)d_in[1];
    const float* bt = (const float*)d_in[2];
    const float* Wp = (const float*)d_in[3];
    const float* bp = (const float*)d_in[4];
    const float* Wg = (const float*)d_in[5];
    const float* bg = (const float*)d_in[6];
    const float* Wo = (const float*)d_in[7];
    const float* bo = (const float*)d_in[8];
    float* out = (float*)d_out;

    unsigned short* xT    = (unsigned short*)d_ws;                  // [B][L][C]  64MB
    unsigned short* w3    = xT + (size_t)B_ * L_ * C_;              // [768][C]   3MB
    unsigned short* wob   = w3 + (size_t)M3_ * C_;                  // [C][M]     1MB
    unsigned short* theta = wob + (size_t)C_ * M_;                  // [B][L][M]  8MB
    unsigned short* phi   = theta + (size_t)B_ * L_ * M_;
    unsigned short* gammaT= phi   + (size_t)B_ * L_ * M_;           // [B][M][L]

    float* yp  = (float*)xT;     // [SPLIT][B][L][M] fp32, 64MB (xT dead after proj)
    float* rsp = (float*)w3;     // [SPLIT][B][L]    fp32 (w3 dead after proj)
    unsigned short* yb = theta;  // [B][L][M] bf16 (theta dead after attn)

    prep_x<<<dim3(L_ / 64, C_ / 32, B_), 256, 0, stream>>>(x, xT);
    prep_w<<<dim3(2097152 / 8 / 256), 256, 0, stream>>>(Wt, Wp, Wg, Wo, w3, wob);
    proj_kernel<<<dim3(L_ / 128, M3_ / 128, B_), 256, 0, stream>>>(
        w3, bt, bp, bg, xT, theta, phi, gammaT);
    attn_kernel<<<dim3(L_ / 256, SPLIT_, B_), 512, 0, stream>>>(
        phi, theta, gammaT, yp, rsp);
    reduce_kernel<<<dim3((B_ * L_ * M_ / 8) / 256), 256, 0, stream>>>(yp, rsp, yb);
    out_kernel<<<dim3(L_ / 128, C_ / 128, B_), 256, 0, stream>>>(x, wob, bo, yb, out);
}